// Round 11
// baseline (137.825 us; speedup 1.0000x reference)
//
#include <hip/hip_runtime.h>
#include <cstdint>
#include <cmath>

#define B_ 2
#define L_ 1024
#define D_ 256
#define U_ 32
#define ROWS_ 2048   // B_*L_
#define WBS 280      // LDS wb row stride (halfwords): 560B, 16B-aligned
#define PSTR 1032    // LDS P row stride (halfwords): 2064B, 16B-aligned

typedef __attribute__((ext_vector_type(8))) short short8;
typedef __attribute__((ext_vector_type(4))) float floatx4;

// ---- workspace layout (bytes) ------------------------------------------------
#define OFF_P  0u                      // [64][2048] f32 = 512 KB (rows 0-31: q2T; 32-63: k2T)
#define OFF_XT (OFF_P + 524288u)       // [B][D][L] bf16 = 1 MB

__device__ __forceinline__ float bf2f(unsigned short u) {
    union { unsigned int i; float f; } v; v.i = ((unsigned int)u) << 16; return v.f;
}
__device__ __forceinline__ unsigned short f2bf(float f) {
    union { float f; unsigned int i; } v; v.f = f;
    unsigned int r = v.i + 0x7FFFu + ((v.i >> 16) & 1u);
    return (unsigned short)(r >> 16);
}
__device__ __forceinline__ unsigned int pack_bf(float a, float b) {
    union { float f; unsigned int i; } ua, ub; ua.f = a; ub.f = b;
    unsigned int ra = ua.i + 0x7FFFu + ((ua.i >> 16) & 1u);
    unsigned int rb = ub.i + 0x7FFFu + ((ub.i >> 16) & 1u);
    return (ra >> 16) | (rb & 0xFFFF0000u);
}

// Inline dtype sniff (per wave). Little-endian: for fp32 data the EVEN ushorts
// are low mantissa halves (garbage exponents, ~18% plausible); for bf16 data
// they are genuine values. Returns 1 = fp32, 0 = bf16.
__device__ __forceinline__ int sniff_is_f32(const void* x) {
    const unsigned short* xu = (const unsigned short*)x;
    float f = bf2f(xu[2 * (threadIdx.x & 63)]);
    bool plausible = (f == f) && (fabsf(f) < 1e4f) && (fabsf(f) > 1e-10f);
    unsigned long long m = __ballot(plausible);
    return (__popcll(m) >= 60) ? 0 : 1;
}

// convert 8 consecutive f32 -> short8 bf16 (RNE)
__device__ __forceinline__ short8 cvt8(const float* p) {
    float4 fa = *(const float4*)p;
    float4 fb = *(const float4*)(p + 4);
    union { short8 s; unsigned int u[4]; } r;
    r.u[0] = pack_bf(fa.x, fa.y);
    r.u[1] = pack_bf(fa.z, fa.w);
    r.u[2] = pack_bf(fb.x, fb.y);
    r.u[3] = pack_bf(fb.z, fb.w);
    return r.s;
}

// ---------------------------------------------------------------------------
// K1 proj_all: per block (64 blocks x 256 thr = 4 waves), rows n0..n0+31:
//   1. stage Wt^T and Wx into LDS wb[64][WBS] bf16 (A-operand layout).
//   2. wave (mt, rh) computes P[u0..u0+31][rows 16rh..+15] via MFMA 16x16x32;
//      B-frags = x rows (read once). mt=0 waves deposit B-frags into xtile.
//   3. coalesced uint stores of xtile -> xT[b][d][l].
// P = SC*(Wb @ x^T [+ bh for u<32]); rows 0-31 = q2T, rows 32-63 = k2T.
// ---------------------------------------------------------------------------
__global__ void proj_all(const void* __restrict__ x,  const void* __restrict__ Wt,
                         const void* __restrict__ Wx, const void* __restrict__ bh,
                         float* __restrict__ P, unsigned short* __restrict__ xT) {
    const int t = threadIdx.x;
    const int isf32 = sniff_is_f32(x);
    const int n0 = blockIdx.x * 32;
    const int b  = n0 >> 10;
    const int l0 = n0 & (L_ - 1);
    __shared__ unsigned short wb[64 * WBS];      // 35.0 KB
    __shared__ unsigned short xtile[D_ * 34];    // 17.0 KB

    for (int j = 0; j < 32; ++j) {
        const int i = t + 256 * j;               // i = d*32 + u
        unsigned short v = isf32 ? f2bf(((const float*)Wt)[i])
                                 : ((const unsigned short*)Wt)[i];
        wb[(i & 31) * WBS + (i >> 5)] = v;
    }
    for (int j = 0; j < 32; ++j) {
        const int e = t + 256 * j;               // e = u*256 + d
        unsigned short v = isf32 ? f2bf(((const float*)Wx)[e])
                                 : ((const unsigned short*)Wx)[e];
        wb[(32 + (e >> 8)) * WBS + (e & 255)] = v;
    }
    __syncthreads();

    const int w    = t >> 6;
    const int lane = t & 63;
    const int mt   = w & 1;         // 0 -> units 0-31 (q), 1 -> units 32-63 (k)
    const int rh   = w >> 1;
    const int m    = lane & 15;
    const int kho  = lane >> 4;
    const int u0   = mt * 32;
    const int row  = n0 + 16 * rh + m;

    floatx4 acc0 = {0,0,0,0}, acc1 = {0,0,0,0};
    #pragma unroll
    for (int k0 = 0; k0 < D_; k0 += 32) {
        const int ks = k0 + kho * 8;
        short8 a0 = *(const short8*)(wb + (u0 + m) * WBS + ks);
        short8 a1 = *(const short8*)(wb + (u0 + 16 + m) * WBS + ks);
        short8 b0;
        if (isf32) b0 = cvt8((const float*)x + (size_t)row * D_ + ks);
        else       b0 = *(const short8*)((const unsigned short*)x + (size_t)row * D_ + ks);
        acc0 = __builtin_amdgcn_mfma_f32_16x16x32_bf16(a0, b0, acc0, 0, 0, 0);
        acc1 = __builtin_amdgcn_mfma_f32_16x16x32_bf16(a1, b0, acc1, 0, 0, 0);
        if (mt == 0) {
            union { short8 s; unsigned short h[8]; } uu; uu.s = b0;
            #pragma unroll
            for (int jj = 0; jj < 8; ++jj)
                xtile[(ks + jj) * 34 + 16 * rh + m] = uu.h[jj];
        }
    }

    const float SC = 2.0f * 1.4426950408889634f;   // 2*log2(e)
    const int col = lane & 15;
    const int rb  = (lane >> 4) * 4;
    #pragma unroll
    for (int r = 0; r < 4; ++r) {
        const int ua = u0 + rb + r, ub_ = u0 + 16 + rb + r;
        float bh0 = 0.f, bh1 = 0.f;
        if (mt == 0) {
            bh0 = isf32 ? ((const float*)bh)[rb + r]      : bf2f(((const unsigned short*)bh)[rb + r]);
            bh1 = isf32 ? ((const float*)bh)[16 + rb + r] : bf2f(((const unsigned short*)bh)[16 + rb + r]);
        }
        P[(size_t)ua  * ROWS_ + n0 + 16 * rh + col] = SC * (acc0[r] + bh0);
        P[(size_t)ub_ * ROWS_ + n0 + 16 * rh + col] = SC * (acc1[r] + bh1);
    }

    __syncthreads();
    unsigned short* xtb = xT + (size_t)b * (D_ * L_) + l0;
    #pragma unroll
    for (int i = 0; i < 16; ++i) {
        const int idx = t + 256 * i;             // idx = d*16 + wq
        const int d = idx >> 4, wq = idx & 15;
        unsigned int p = *(const unsigned int*)(xtile + d * 34 + 2 * wq);
        *(unsigned int*)(xtb + (size_t)d * L_ + 2 * wq) = p;
    }
}

// ---------------------------------------------------------------------------
// K2 alpha_pv: FUSED alpha+softmax+PV. 256 blocks x 512 thr (8 waves), 1/CU.
// __launch_bounds__(512, 2): 2 waves/SIMD -> 256-VGPR budget. CRITICAL: the
// default cap (64 VGPR) spilled qv/wv/alp to scratch -- 48 us (R10). ~80 live
// floats/thread need the headroom; grid is 1 block/CU regardless.
// Phase 1: wave w owns q-row blk*8+w. alpha_eff[key] = sum_u (-2*Wa[u]) *
//   rcp(exp2(q2T[u][row]+k2T[u][key])+1) (consts ba, sum Wa dropped --
//   softmax-invariant). Wave softmax; normalized bf16 row -> LDS Pl[w][*].
// Phase 2: PV via MFMA 16x16x32: A = Pl rows (m 0-7 valid), B = xT d-slice
//   (wave w -> d = 32w..32w+31). Stores C rows < 8 at out[b][qi0+row][d].
// ---------------------------------------------------------------------------
__global__ __launch_bounds__(512, 2) void alpha_pv(const float* __restrict__ P,
                                                   const void* __restrict__ Wa,
                                                   const void* __restrict__ x,
                                                   const unsigned short* __restrict__ xT,
                                                   void* __restrict__ out) {
    const int w    = threadIdx.x >> 6;       // 0..7
    const int lane = threadIdx.x & 63;
    const int row  = blockIdx.x * 8 + w;     // global row = b*L + qi
    const int b    = row >> 10;
    const int isf32 = sniff_is_f32(x);
    __shared__ unsigned short Pl[16 * PSTR];   // 33 KB

    // ---- phase 1: alpha + softmax
    float qv[U_], wv[U_];
    #pragma unroll
    for (int u = 0; u < U_; ++u) qv[u] = P[(size_t)u * ROWS_ + row];   // uniform
    if (isf32) {
        #pragma unroll
        for (int i = 0; i < U_ / 4; ++i) {
            float4 tw = ((const float4*)Wa)[i];
            wv[4*i+0] = -2.f*tw.x; wv[4*i+1] = -2.f*tw.y; wv[4*i+2] = -2.f*tw.z; wv[4*i+3] = -2.f*tw.w;
        }
    } else {
        #pragma unroll
        for (int i = 0; i < U_ / 4; ++i) {
            ushort4 tw = ((const ushort4*)Wa)[i];
            wv[4*i+0] = -2.f*bf2f(tw.x); wv[4*i+1] = -2.f*bf2f(tw.y);
            wv[4*i+2] = -2.f*bf2f(tw.z); wv[4*i+3] = -2.f*bf2f(tw.w);
        }
    }

    const float* kb = P + (size_t)32 * ROWS_ + (size_t)b * L_;   // k2T[u][key]
    float alp[16];
    float amax = -1e30f;
    #pragma unroll
    for (int jj = 0; jj < 4; ++jj) {
        float ac0 = 0.f, ac1 = 0.f, ac2 = 0.f, ac3 = 0.f;
        #pragma unroll 16
        for (int u = 0; u < U_; ++u) {
            float4 kk = *(const float4*)(kb + (size_t)u * ROWS_ + jj * 256 + 4 * lane);
            float e0 = __builtin_amdgcn_exp2f(qv[u] + kk.x);
            float e1 = __builtin_amdgcn_exp2f(qv[u] + kk.y);
            float e2 = __builtin_amdgcn_exp2f(qv[u] + kk.z);
            float e3 = __builtin_amdgcn_exp2f(qv[u] + kk.w);
            ac0 = fmaf(wv[u], __builtin_amdgcn_rcpf(e0 + 1.0f), ac0);
            ac1 = fmaf(wv[u], __builtin_amdgcn_rcpf(e1 + 1.0f), ac1);
            ac2 = fmaf(wv[u], __builtin_amdgcn_rcpf(e2 + 1.0f), ac2);
            ac3 = fmaf(wv[u], __builtin_amdgcn_rcpf(e3 + 1.0f), ac3);
        }
        alp[4*jj+0] = ac0; alp[4*jj+1] = ac1; alp[4*jj+2] = ac2; alp[4*jj+3] = ac3;
        amax = fmaxf(amax, fmaxf(fmaxf(ac0, ac1), fmaxf(ac2, ac3)));
    }
    #pragma unroll
    for (int off = 32; off > 0; off >>= 1) amax = fmaxf(amax, __shfl_xor(amax, off, 64));

    const float L2E = 1.4426950408889634f;
    float s = 0.f;
    #pragma unroll
    for (int j = 0; j < 16; ++j) {
        alp[j] = __builtin_amdgcn_exp2f((alp[j] - amax) * L2E);
        s += alp[j];
    }
    #pragma unroll
    for (int off = 32; off > 0; off >>= 1) s += __shfl_xor(s, off, 64);
    const float rinv = __builtin_amdgcn_rcpf(s);

    #pragma unroll
    for (int jj = 0; jj < 4; ++jj) {
        ushort4 pk;
        pk.x = f2bf(alp[4*jj+0] * rinv);
        pk.y = f2bf(alp[4*jj+1] * rinv);
        pk.z = f2bf(alp[4*jj+2] * rinv);
        pk.w = f2bf(alp[4*jj+3] * rinv);
        *(ushort4*)(Pl + w * PSTR + jj * 256 + 4 * lane) = pk;   // key = jj*256+4*lane+c
    }
    __syncthreads();

    // ---- phase 2: PV.  wave w -> d-slice [32w, 32w+32)
    const int m  = lane & 15;
    const int ko = (lane >> 4) * 8;
    const int d0 = w * 32;
    const unsigned short* xb0 = xT + (size_t)b * (D_ * L_) + (size_t)(d0 + m) * L_ + ko;
    const unsigned short* xb1 = xb0 + (size_t)16 * L_;
    const unsigned short* pp  = Pl + (size_t)m * PSTR + ko;

    floatx4 acc0 = {0,0,0,0}, acc1 = {0,0,0,0};
    short8 pa = *(const short8*)(pp);
    short8 x0 = *(const short8*)(xb0);
    short8 x1 = *(const short8*)(xb1);
    for (int ks = 32; ks < L_; ks += 32) {
        short8 npa = *(const short8*)(pp + ks);
        short8 nx0 = *(const short8*)(xb0 + ks);
        short8 nx1 = *(const short8*)(xb1 + ks);
        acc0 = __builtin_amdgcn_mfma_f32_16x16x32_bf16(pa, x0, acc0, 0, 0, 0);
        acc1 = __builtin_amdgcn_mfma_f32_16x16x32_bf16(pa, x1, acc1, 0, 0, 0);
        pa = npa; x0 = nx0; x1 = nx1;
    }
    acc0 = __builtin_amdgcn_mfma_f32_16x16x32_bf16(pa, x0, acc0, 0, 0, 0);
    acc1 = __builtin_amdgcn_mfma_f32_16x16x32_bf16(pa, x1, acc1, 0, 0, 0);

    // C/D layout: col = lane&15 (= d offset), row = (lane>>4)*4 + reg (= q)
    const int col = lane & 15;
    const int rb  = (lane >> 4) * 4;
    const int qi0 = (blockIdx.x * 8) & (L_ - 1);   // LOCAL q index (mask out batch)
    const size_t obase = (size_t)b * (L_ * D_) + (size_t)qi0 * D_;
    if (rb < 8) {   // lanes 0-31 hold valid q-rows 0-7
        if (isf32) {
            float* ob = (float*)out + obase;
            #pragma unroll
            for (int r = 0; r < 4; ++r) {
                ob[(size_t)(rb + r) * D_ + d0 + col]      = acc0[r];
                ob[(size_t)(rb + r) * D_ + d0 + 16 + col] = acc1[r];
            }
        } else {
            unsigned short* ob = (unsigned short*)out + obase;
            #pragma unroll
            for (int r = 0; r < 4; ++r) {
                ob[(size_t)(rb + r) * D_ + d0 + col]      = f2bf(acc0[r]);
                ob[(size_t)(rb + r) * D_ + d0 + 16 + col] = f2bf(acc1[r]);
            }
        }
    }
}

extern "C" void kernel_launch(void* const* d_in, const int* in_sizes, int n_in,
                              void* d_out, int out_size, void* d_ws, size_t ws_size,
                              hipStream_t stream) {
    const void* x  = d_in[0];   // [B,L,D]  dtype sniffed at runtime (fp32 expected)
    const void* Wt = d_in[1];   // [D,U]
    const void* Wx = d_in[2];   // [U,D]
    const void* bh = d_in[3];   // [U]
    const void* Wa = d_in[4];   // [U,1]
    // d_in[5] = ba: constant pre-softmax shift -> mathematically irrelevant.

    char* ws = (char*)d_ws;
    float*          P   = (float*)(ws + OFF_P);
    unsigned short* xT  = (unsigned short*)(ws + OFF_XT);

    proj_all<<<ROWS_ / 32, 256, 0, stream>>>(x, Wt, Wx, bh, P, xT);
    alpha_pv<<<ROWS_ / 8, 512, 0, stream>>>(P, Wa, x, xT, d_out);
}

// Round 12
// 112.705 us; speedup vs baseline: 1.2229x; 1.2229x over previous
//
#include <hip/hip_runtime.h>
#include <cstdint>
#include <cmath>

#define B_ 2
#define L_ 1024
#define D_ 256
#define U_ 32
#define ROWS_ 2048   // B_*L_
#define WBS 280      // LDS wb row stride (halfwords): 560B, 16B-aligned
#define PSTR 1032    // LDS P row stride (halfwords): 2064B, 16B-aligned

typedef __attribute__((ext_vector_type(8))) short short8;
typedef __attribute__((ext_vector_type(4))) float floatx4;

// ---- workspace layout (bytes) ------------------------------------------------
// P now holds EXP2 of the scaled logits: rows 0-31: equ = exp2(SC*(q·Wt+bh));
// rows 32-63: ekk = exp2(SC*(k·Wx)).  exp2(qu+kk) == equ*ekk (hoisted).
#define OFF_P  0u                      // [64][2048] f32 = 512 KB
#define OFF_XT (OFF_P + 524288u)       // [B][D][L] bf16 = 1 MB
#define OFF_WV (OFF_XT + 1048576u)     // [32] f32 = 128 B  (-2*Wa)

__device__ __forceinline__ float bf2f(unsigned short u) {
    union { unsigned int i; float f; } v; v.i = ((unsigned int)u) << 16; return v.f;
}
__device__ __forceinline__ unsigned short f2bf(float f) {
    union { float f; unsigned int i; } v; v.f = f;
    unsigned int r = v.i + 0x7FFFu + ((v.i >> 16) & 1u);
    return (unsigned short)(r >> 16);
}
__device__ __forceinline__ unsigned int pack_bf(float a, float b) {
    union { float f; unsigned int i; } ua, ub; ua.f = a; ub.f = b;
    unsigned int ra = ua.i + 0x7FFFu + ((ua.i >> 16) & 1u);
    unsigned int rb = ub.i + 0x7FFFu + ((ub.i >> 16) & 1u);
    return (ra >> 16) | (rb & 0xFFFF0000u);
}

// Inline dtype sniff (per wave). Little-endian: for fp32 data the EVEN ushorts
// are low mantissa halves (garbage exponents, ~18% plausible); for bf16 data
// they are genuine values. Returns 1 = fp32, 0 = bf16.
__device__ __forceinline__ int sniff_is_f32(const void* x) {
    const unsigned short* xu = (const unsigned short*)x;
    float f = bf2f(xu[2 * (threadIdx.x & 63)]);
    bool plausible = (f == f) && (fabsf(f) < 1e4f) && (fabsf(f) > 1e-10f);
    unsigned long long m = __ballot(plausible);
    return (__popcll(m) >= 60) ? 0 : 1;
}

// convert 8 consecutive f32 -> short8 bf16 (RNE)
__device__ __forceinline__ short8 cvt8(const float* p) {
    float4 fa = *(const float4*)p;
    float4 fb = *(const float4*)(p + 4);
    union { short8 s; unsigned int u[4]; } r;
    r.u[0] = pack_bf(fa.x, fa.y);
    r.u[1] = pack_bf(fa.z, fa.w);
    r.u[2] = pack_bf(fb.x, fb.y);
    r.u[3] = pack_bf(fb.z, fb.w);
    return r.s;
}

// ---------------------------------------------------------------------------
// K1 proj_all: per block (64 blocks x 256 thr = 4 waves), rows n0..n0+31:
//   1. stage Wt^T and Wx into LDS wb[64][WBS] bf16 (A-operand layout).
//   2. wave (mt, rh) computes logits via MFMA 16x16x32; B-frags = x rows
//      (read once). mt=0 waves deposit B-frags into xtile.
//   3. P stores EXP2 of the scaled logits (hoists exp2 out of alpha's O(L^2)
//      inner loop: exp2(qu+kk) = equ*ekk).
//   4. coalesced uint stores of xtile -> xT[b][d][l].
// Block 0 also precomputes WV[u] = -2*Wa[u] (f32).
// ---------------------------------------------------------------------------
__global__ void proj_all(const void* __restrict__ x,  const void* __restrict__ Wt,
                         const void* __restrict__ Wx, const void* __restrict__ bh,
                         const void* __restrict__ Wa,
                         float* __restrict__ P, unsigned short* __restrict__ xT,
                         float* __restrict__ WV) {
    const int t = threadIdx.x;
    const int isf32 = sniff_is_f32(x);
    const int n0 = blockIdx.x * 32;
    const int b  = n0 >> 10;
    const int l0 = n0 & (L_ - 1);
    __shared__ unsigned short wb[64 * WBS];      // 35.0 KB
    __shared__ unsigned short xtile[D_ * 34];    // 17.0 KB

    if (blockIdx.x == 0 && t < U_) {
        float wav = isf32 ? ((const float*)Wa)[t] : bf2f(((const unsigned short*)Wa)[t]);
        WV[t] = -2.0f * wav;
    }

    for (int j = 0; j < 32; ++j) {
        const int i = t + 256 * j;               // i = d*32 + u
        unsigned short v = isf32 ? f2bf(((const float*)Wt)[i])
                                 : ((const unsigned short*)Wt)[i];
        wb[(i & 31) * WBS + (i >> 5)] = v;
    }
    for (int j = 0; j < 32; ++j) {
        const int e = t + 256 * j;               // e = u*256 + d
        unsigned short v = isf32 ? f2bf(((const float*)Wx)[e])
                                 : ((const unsigned short*)Wx)[e];
        wb[(32 + (e >> 8)) * WBS + (e & 255)] = v;
    }
    __syncthreads();

    const int w    = t >> 6;
    const int lane = t & 63;
    const int mt   = w & 1;         // 0 -> units 0-31 (q), 1 -> units 32-63 (k)
    const int rh   = w >> 1;
    const int m    = lane & 15;
    const int kho  = lane >> 4;
    const int u0   = mt * 32;
    const int row  = n0 + 16 * rh + m;

    floatx4 acc0 = {0,0,0,0}, acc1 = {0,0,0,0};
    #pragma unroll
    for (int k0 = 0; k0 < D_; k0 += 32) {
        const int ks = k0 + kho * 8;
        short8 a0 = *(const short8*)(wb + (u0 + m) * WBS + ks);
        short8 a1 = *(const short8*)(wb + (u0 + 16 + m) * WBS + ks);
        short8 b0;
        if (isf32) b0 = cvt8((const float*)x + (size_t)row * D_ + ks);
        else       b0 = *(const short8*)((const unsigned short*)x + (size_t)row * D_ + ks);
        acc0 = __builtin_amdgcn_mfma_f32_16x16x32_bf16(a0, b0, acc0, 0, 0, 0);
        acc1 = __builtin_amdgcn_mfma_f32_16x16x32_bf16(a1, b0, acc1, 0, 0, 0);
        if (mt == 0) {
            union { short8 s; unsigned short h[8]; } uu; uu.s = b0;
            #pragma unroll
            for (int jj = 0; jj < 8; ++jj)
                xtile[(ks + jj) * 34 + 16 * rh + m] = uu.h[jj];
        }
    }

    const float SC = 2.0f * 1.4426950408889634f;   // 2*log2(e)
    const int col = lane & 15;
    const int rb  = (lane >> 4) * 4;
    #pragma unroll
    for (int r = 0; r < 4; ++r) {
        const int ua = u0 + rb + r, ub_ = u0 + 16 + rb + r;
        float bh0 = 0.f, bh1 = 0.f;
        if (mt == 0) {
            bh0 = isf32 ? ((const float*)bh)[rb + r]      : bf2f(((const unsigned short*)bh)[rb + r]);
            bh1 = isf32 ? ((const float*)bh)[16 + rb + r] : bf2f(((const unsigned short*)bh)[16 + rb + r]);
        }
        P[(size_t)ua  * ROWS_ + n0 + 16 * rh + col] = __builtin_amdgcn_exp2f(SC * (acc0[r] + bh0));
        P[(size_t)ub_ * ROWS_ + n0 + 16 * rh + col] = __builtin_amdgcn_exp2f(SC * (acc1[r] + bh1));
    }

    __syncthreads();
    unsigned short* xtb = xT + (size_t)b * (D_ * L_) + l0;
    #pragma unroll
    for (int i = 0; i < 16; ++i) {
        const int idx = t + 256 * i;             // idx = d*16 + wq
        const int d = idx >> 4, wq = idx & 15;
        unsigned int p = *(const unsigned int*)(xtile + d * 34 + 2 * wq);
        *(unsigned int*)(xtb + (size_t)d * L_ + 2 * wq) = p;
    }
}

// ---------------------------------------------------------------------------
// K2 alpha_pv: FUSED alpha+softmax+PV. 256 blocks x 512 thr (8 waves), 1/CU.
// Phase 1 (u-OUTER loop -- keeps live set ~45 VGPRs; R10/R11's q-hoisted form
// forced remat/spill of 80 floats => 5x slowdown):
//   per u: equ, wu uniform loads; 4x float4 of ekk row; 16x {fma,rcp,fma}.
//   alpha_eff[key] = sum_u wu * rcp(equ*ekk + 1)   (wu = -2*Wa[u]; consts
//   dropped -- softmax invariant; exp2 pre-hoisted into P by proj_all).
// Wave softmax; normalized bf16 row -> LDS Pl[w][*] (A-frag layout).
// Phase 2: PV via MFMA 16x16x32: A = Pl rows (m 0-7 valid), B = xT d-slice
//   (wave w -> d = 32w..32w+31). Stores C rows < 8 at out[b][qi0+r][d].
// ---------------------------------------------------------------------------
__global__ __launch_bounds__(512) void alpha_pv(const float* __restrict__ P,
                                                const float* __restrict__ WV,
                                                const void* __restrict__ x,
                                                const unsigned short* __restrict__ xT,
                                                void* __restrict__ out) {
    const int w    = threadIdx.x >> 6;       // 0..7
    const int lane = threadIdx.x & 63;
    const int row  = blockIdx.x * 8 + w;     // global row = b*L + qi
    const int b    = row >> 10;
    const int isf32 = sniff_is_f32(x);
    __shared__ unsigned short Pl[16 * PSTR];   // 33 KB

    // ---- phase 1: alpha + softmax (u-outer; lane holds keys jj*256+4*lane+c)
    const float* Pq = P + row;                              // equ: stride ROWS_ per u
    const float* kb = P + (size_t)32 * ROWS_ + (size_t)b * L_ + 4 * lane;
    float alp[16];
    #pragma unroll
    for (int j = 0; j < 16; ++j) alp[j] = 0.f;

    #pragma unroll 2
    for (int u = 0; u < U_; ++u) {
        const float equ = Pq[(size_t)u * ROWS_];            // uniform broadcast
        const float wu  = WV[u];                            // uniform broadcast
        const float* kr = kb + (size_t)u * ROWS_;
        float4 k0 = *(const float4*)(kr);
        float4 k1 = *(const float4*)(kr + 256);
        float4 k2 = *(const float4*)(kr + 512);
        float4 k3 = *(const float4*)(kr + 768);
        alp[0]  = fmaf(wu, __builtin_amdgcn_rcpf(fmaf(equ, k0.x, 1.f)), alp[0]);
        alp[1]  = fmaf(wu, __builtin_amdgcn_rcpf(fmaf(equ, k0.y, 1.f)), alp[1]);
        alp[2]  = fmaf(wu, __builtin_amdgcn_rcpf(fmaf(equ, k0.z, 1.f)), alp[2]);
        alp[3]  = fmaf(wu, __builtin_amdgcn_rcpf(fmaf(equ, k0.w, 1.f)), alp[3]);
        alp[4]  = fmaf(wu, __builtin_amdgcn_rcpf(fmaf(equ, k1.x, 1.f)), alp[4]);
        alp[5]  = fmaf(wu, __builtin_amdgcn_rcpf(fmaf(equ, k1.y, 1.f)), alp[5]);
        alp[6]  = fmaf(wu, __builtin_amdgcn_rcpf(fmaf(equ, k1.z, 1.f)), alp[6]);
        alp[7]  = fmaf(wu, __builtin_amdgcn_rcpf(fmaf(equ, k1.w, 1.f)), alp[7]);
        alp[8]  = fmaf(wu, __builtin_amdgcn_rcpf(fmaf(equ, k2.x, 1.f)), alp[8]);
        alp[9]  = fmaf(wu, __builtin_amdgcn_rcpf(fmaf(equ, k2.y, 1.f)), alp[9]);
        alp[10] = fmaf(wu, __builtin_amdgcn_rcpf(fmaf(equ, k2.z, 1.f)), alp[10]);
        alp[11] = fmaf(wu, __builtin_amdgcn_rcpf(fmaf(equ, k2.w, 1.f)), alp[11]);
        alp[12] = fmaf(wu, __builtin_amdgcn_rcpf(fmaf(equ, k3.x, 1.f)), alp[12]);
        alp[13] = fmaf(wu, __builtin_amdgcn_rcpf(fmaf(equ, k3.y, 1.f)), alp[13]);
        alp[14] = fmaf(wu, __builtin_amdgcn_rcpf(fmaf(equ, k3.z, 1.f)), alp[14]);
        alp[15] = fmaf(wu, __builtin_amdgcn_rcpf(fmaf(equ, k3.w, 1.f)), alp[15]);
    }

    float amax = alp[0];
    #pragma unroll
    for (int j = 1; j < 16; ++j) amax = fmaxf(amax, alp[j]);
    #pragma unroll
    for (int off = 32; off > 0; off >>= 1) amax = fmaxf(amax, __shfl_xor(amax, off, 64));

    const float L2E = 1.4426950408889634f;
    float s = 0.f;
    #pragma unroll
    for (int j = 0; j < 16; ++j) {
        alp[j] = __builtin_amdgcn_exp2f((alp[j] - amax) * L2E);
        s += alp[j];
    }
    #pragma unroll
    for (int off = 32; off > 0; off >>= 1) s += __shfl_xor(s, off, 64);
    const float rinv = __builtin_amdgcn_rcpf(s);

    #pragma unroll
    for (int jj = 0; jj < 4; ++jj) {
        ushort4 pk;
        pk.x = f2bf(alp[4*jj+0] * rinv);
        pk.y = f2bf(alp[4*jj+1] * rinv);
        pk.z = f2bf(alp[4*jj+2] * rinv);
        pk.w = f2bf(alp[4*jj+3] * rinv);
        *(ushort4*)(Pl + w * PSTR + jj * 256 + 4 * lane) = pk;   // key = jj*256+4*lane+c
    }
    __syncthreads();

    // ---- phase 2: PV.  wave w -> d-slice [32w, 32w+32)
    const int m  = lane & 15;
    const int ko = (lane >> 4) * 8;
    const int d0 = w * 32;
    const unsigned short* xb0 = xT + (size_t)b * (D_ * L_) + (size_t)(d0 + m) * L_ + ko;
    const unsigned short* xb1 = xb0 + (size_t)16 * L_;
    const unsigned short* pp  = Pl + (size_t)m * PSTR + ko;

    floatx4 acc0 = {0,0,0,0}, acc1 = {0,0,0,0};
    short8 pa = *(const short8*)(pp);
    short8 x0 = *(const short8*)(xb0);
    short8 x1 = *(const short8*)(xb1);
    for (int ks = 32; ks < L_; ks += 32) {
        short8 npa = *(const short8*)(pp + ks);
        short8 nx0 = *(const short8*)(xb0 + ks);
        short8 nx1 = *(const short8*)(xb1 + ks);
        acc0 = __builtin_amdgcn_mfma_f32_16x16x32_bf16(pa, x0, acc0, 0, 0, 0);
        acc1 = __builtin_amdgcn_mfma_f32_16x16x32_bf16(pa, x1, acc1, 0, 0, 0);
        pa = npa; x0 = nx0; x1 = nx1;
    }
    acc0 = __builtin_amdgcn_mfma_f32_16x16x32_bf16(pa, x0, acc0, 0, 0, 0);
    acc1 = __builtin_amdgcn_mfma_f32_16x16x32_bf16(pa, x1, acc1, 0, 0, 0);

    // C/D layout: col = lane&15 (= d offset), row = (lane>>4)*4 + reg (= q)
    const int col = lane & 15;
    const int rb  = (lane >> 4) * 4;
    const int qi0 = (blockIdx.x * 8) & (L_ - 1);   // LOCAL q index (mask out batch)
    const size_t obase = (size_t)b * (L_ * D_) + (size_t)qi0 * D_;
    if (rb < 8) {   // lanes 0-31 hold valid q-rows 0-7
        if (isf32) {
            float* ob = (float*)out + obase;
            #pragma unroll
            for (int r = 0; r < 4; ++r) {
                ob[(size_t)(rb + r) * D_ + d0 + col]      = acc0[r];
                ob[(size_t)(rb + r) * D_ + d0 + 16 + col] = acc1[r];
            }
        } else {
            unsigned short* ob = (unsigned short*)out + obase;
            #pragma unroll
            for (int r = 0; r < 4; ++r) {
                ob[(size_t)(rb + r) * D_ + d0 + col]      = f2bf(acc0[r]);
                ob[(size_t)(rb + r) * D_ + d0 + 16 + col] = f2bf(acc1[r]);
            }
        }
    }
}

extern "C" void kernel_launch(void* const* d_in, const int* in_sizes, int n_in,
                              void* d_out, int out_size, void* d_ws, size_t ws_size,
                              hipStream_t stream) {
    const void* x  = d_in[0];   // [B,L,D]  dtype sniffed at runtime (fp32 expected)
    const void* Wt = d_in[1];   // [D,U]
    const void* Wx = d_in[2];   // [U,D]
    const void* bh = d_in[3];   // [U]
    const void* Wa = d_in[4];   // [U,1]
    // d_in[5] = ba: constant pre-softmax shift -> mathematically irrelevant.

    char* ws = (char*)d_ws;
    float*          P   = (float*)(ws + OFF_P);
    unsigned short* xT  = (unsigned short*)(ws + OFF_XT);
    float*          WV  = (float*)(ws + OFF_WV);

    proj_all<<<ROWS_ / 32, 256, 0, stream>>>(x, Wt, Wx, bh, Wa, P, xT, WV);
    alpha_pv<<<ROWS_ / 8, 512, 0, stream>>>(P, WV, x, xT, d_out);
}